// Round 1
// baseline (426.332 us; speedup 1.0000x reference)
//
#include <hip/hip_runtime.h>
#include <hip/hip_bf16.h>

// WindowAttention: B_=4096 windows, N=64 tokens, C=256, H=8 heads, hd=32.
// Fully fused: one workgroup per window, 8 waves, wave h owns head h.
// bf16 MFMA (16x16x32), fp32 accumulate, fp32 softmax, fp32 output.

typedef __attribute__((ext_vector_type(8))) short bf16x8;   // 8 bf16 = 4 VGPR
typedef __attribute__((ext_vector_type(4))) float f32x4;    // MFMA acc

struct alignas(8) us4 { unsigned short x, y, z, w; };

__device__ inline unsigned short f2bf(float f) {
    // round-to-nearest-even f32 -> bf16
    unsigned u = __builtin_bit_cast(unsigned, f);
    u += 0x7fffu + ((u >> 16) & 1u);
    return (unsigned short)(u >> 16);
}

__device__ inline f32x4 mfma16(bf16x8 a, bf16x8 b, f32x4 c) {
    return __builtin_amdgcn_mfma_f32_16x16x32_bf16(a, b, c, 0, 0, 0);
}

__device__ inline bf16x8 lds8(const unsigned short* p) {
    return *reinterpret_cast<const bf16x8*>(p);
}

// ---------------- prep: weight casts + dense bias gather --------------------
__global__ void prep_kernel(const float* __restrict__ qkv_w,
                            const float* __restrict__ proj_w,
                            const float* __restrict__ bias_table,
                            const int*   __restrict__ rel_index,
                            unsigned short* __restrict__ qkv_wb,
                            unsigned short* __restrict__ proj_wb,
                            float* __restrict__ biasF) {
    int stride = gridDim.x * blockDim.x;
    int t0 = blockIdx.x * blockDim.x + threadIdx.x;
    for (int i = t0; i < 768 * 256; i += stride) qkv_wb[i] = f2bf(qkv_w[i]);
    for (int i = t0; i < 256 * 256; i += stride) proj_wb[i] = f2bf(proj_w[i]);
    for (int i = t0; i < 8 * 64 * 64; i += stride) {
        int h = i >> 12, rem = i & 4095, m = rem >> 6, n = rem & 63;
        // bias[h][query m][key n] = table[rel_index[m][n]][h]
        biasF[i] = bias_table[rel_index[m * 64 + n] * 8 + h];
    }
}

// ---------------- fused window attention ------------------------------------
// LDS layout (ushort units), total 76288 ushorts = 152576 B:
//   XB   @ 0      : x bf16 [64][264]  (16896) ; reused as attn_out in phase 3
//   QK   @ 16896  : per head h (5120): q [64][40] @ +0, k [64][40] @ +2560
//                   (P [64][72] = 4608 overwrites q/k after QK^T, wave-local)
//   VT   @ 57856  : per head h (2304): vT [32][72]  (v transposed, d-major)
__global__ __launch_bounds__(512, 2) void win_attn_kernel(
    const float* __restrict__ x,
    const float* __restrict__ qkv_b,
    const float* __restrict__ proj_b,
    const unsigned short* __restrict__ qkv_wb,
    const unsigned short* __restrict__ proj_wb,
    const float* __restrict__ biasF,
    float* __restrict__ out)
{
    __shared__ unsigned short sm[76288];
    const int tid  = threadIdx.x;
    const int wid  = tid >> 6;
    const int lane = tid & 63;
    const int r16  = lane & 15;
    const int g    = lane >> 4;
    const int win  = blockIdx.x;
    const float* xg = x + (size_t)win * 16384;

    // ---- Phase 0: x -> xb (bf16, padded rows of 264) ----
#pragma unroll
    for (int i = 0; i < 8; ++i) {
        int flat = i * 2048 + tid * 4;
        float4 v = *reinterpret_cast<const float4*>(xg + flat);
        int row = flat >> 8, col = flat & 255;
        us4 pk = { f2bf(v.x), f2bf(v.y), f2bf(v.z), f2bf(v.w) };
        *reinterpret_cast<us4*>(&sm[row * 264 + col]) = pk;
    }
    __syncthreads();

    // ---- Phase 1: QKV GEMM, wave h computes head h's q,k,v ----
    const int h = wid;
    int ntb[6];
    ntb[0] = 2 * h;      ntb[1] = 2 * h + 1;
    ntb[2] = 16 + 2 * h; ntb[3] = 17 + 2 * h;
    ntb[4] = 32 + 2 * h; ntb[5] = 33 + 2 * h;

    const f32x4 zero4 = {0.f, 0.f, 0.f, 0.f};
    f32x4 acc[4][6];
#pragma unroll
    for (int a = 0; a < 4; ++a)
#pragma unroll
        for (int b = 0; b < 6; ++b) acc[a][b] = zero4;

#pragma unroll
    for (int ks = 0; ks < 8; ++ks) {
        bf16x8 af[4];
#pragma unroll
        for (int mt = 0; mt < 4; ++mt)
            af[mt] = lds8(&sm[(mt * 16 + r16) * 264 + ks * 32 + g * 8]);
#pragma unroll
        for (int ni = 0; ni < 6; ++ni) {
            const unsigned short* wp =
                qkv_wb + (ntb[ni] * 16 + r16) * 256 + ks * 32 + g * 8;
            bf16x8 bf = *reinterpret_cast<const bf16x8*>(wp);
#pragma unroll
            for (int mt = 0; mt < 4; ++mt)
                acc[mt][ni] = mfma16(af[mt], bf, acc[mt][ni]);
        }
    }

    const int qbase = 16896 + h * 5120;
    const int kbase = qbase + 2560;
    const int vtb   = 57856 + h * 2304;

#pragma unroll
    for (int ni = 0; ni < 6; ++ni) {
        int n = ntb[ni] * 16 + r16;          // global channel in [0,768)
        float qb = qkv_b[n];
        int d = (ni & 1) * 16 + r16;         // channel within head [0,32)
#pragma unroll
        for (int mt = 0; mt < 4; ++mt) {
            f32x4 a4 = acc[mt][ni];
            if (ni < 2) {                    // q: [64 rows][40] d-contig
#pragma unroll
                for (int j = 0; j < 4; ++j)
                    sm[qbase + (mt * 16 + g * 4 + j) * 40 + d] = f2bf(a4[j] + qb);
            } else if (ni < 4) {             // k: [64 rows][40]
#pragma unroll
                for (int j = 0; j < 4; ++j)
                    sm[kbase + (mt * 16 + g * 4 + j) * 40 + d] = f2bf(a4[j] + qb);
            } else {                         // v transposed: vT[d][m], m-contig
                us4 pk = { f2bf(a4[0] + qb), f2bf(a4[1] + qb),
                           f2bf(a4[2] + qb), f2bf(a4[3] + qb) };
                *reinterpret_cast<us4*>(&sm[vtb + d * 72 + mt * 16 + g * 4]) = pk;
            }
        }
    }
    // protects: all waves done reading xb before attn_out overwrites it
    __syncthreads();

    // ---- Phase 2: attention for head h (wave-local) ----
    // Swapped QK^T: S^T = K · Q^T  (D rows = keys, D cols = queries)
    bf16x8 ak[4], bq[4];
#pragma unroll
    for (int t = 0; t < 4; ++t) {
        ak[t] = lds8(&sm[kbase + (t * 16 + r16) * 40 + g * 8]);
        bq[t] = lds8(&sm[qbase + (t * 16 + r16) * 40 + g * 8]);
    }
    f32x4 st[4][4];
#pragma unroll
    for (int rt = 0; rt < 4; ++rt)
#pragma unroll
        for (int ct = 0; ct < 4; ++ct)
            st[rt][ct] = mfma16(ak[rt], bq[ct], zero4);

    const float scale = 0.1767766952966369f;   // 1/sqrt(32)
    const float* bh = biasF + h * 4096;

    // softmax over keys; P (bf16, /sum folded in) overwrites q/k region
#pragma unroll
    for (int ct = 0; ct < 4; ++ct) {
        int m = ct * 16 + r16;                 // query row
        float pv[4][4];
        float mx = -1e30f;
#pragma unroll
        for (int rt = 0; rt < 4; ++rt) {
            float4 b4 = *reinterpret_cast<const float4*>(bh + m * 64 + rt * 16 + g * 4);
            float bb[4] = { b4.x, b4.y, b4.z, b4.w };
#pragma unroll
            for (int j = 0; j < 4; ++j) {
                float v = st[rt][ct][j] * scale + bb[j];
                pv[rt][j] = v;
                mx = fmaxf(mx, v);
            }
        }
        mx = fmaxf(mx, __shfl_xor(mx, 16));
        mx = fmaxf(mx, __shfl_xor(mx, 32));
        float s = 0.f;
#pragma unroll
        for (int rt = 0; rt < 4; ++rt)
#pragma unroll
            for (int j = 0; j < 4; ++j) {
                float e = __expf(pv[rt][j] - mx);
                pv[rt][j] = e;
                s += e;
            }
        s += __shfl_xor(s, 16);
        s += __shfl_xor(s, 32);
        float inv = 1.f / s;
#pragma unroll
        for (int rt = 0; rt < 4; ++rt) {
            us4 pk = { f2bf(pv[rt][0] * inv), f2bf(pv[rt][1] * inv),
                       f2bf(pv[rt][2] * inv), f2bf(pv[rt][3] * inv) };
            *reinterpret_cast<us4*>(&sm[qbase + m * 72 + rt * 16 + g * 4]) = pk;
        }
    }
    // same-wave DS ordering guarantees P writes precede reads below; make the
    // wait explicit for safety.
    asm volatile("s_waitcnt lgkmcnt(0)" ::: "memory");

    // PV: out_h[64][32] = P[64][64] @ v_h[64][32]  (B-frag from vT, contiguous)
    f32x4 o[4][2];
#pragma unroll
    for (int mt = 0; mt < 4; ++mt)
#pragma unroll
        for (int nt = 0; nt < 2; ++nt) o[mt][nt] = zero4;
#pragma unroll
    for (int ks = 0; ks < 2; ++ks) {
        bf16x8 ap[4];
#pragma unroll
        for (int mt = 0; mt < 4; ++mt)
            ap[mt] = lds8(&sm[qbase + (mt * 16 + r16) * 72 + ks * 32 + g * 8]);
#pragma unroll
        for (int nt = 0; nt < 2; ++nt) {
            bf16x8 bv = lds8(&sm[vtb + (nt * 16 + r16) * 72 + ks * 32 + g * 8]);
#pragma unroll
            for (int mt = 0; mt < 4; ++mt)
                o[mt][nt] = mfma16(ap[mt], bv, o[mt][nt]);
        }
    }
    // scatter head output into attn_out [64][264] (overlays dead xb)
#pragma unroll
    for (int mt = 0; mt < 4; ++mt)
#pragma unroll
        for (int nt = 0; nt < 2; ++nt)
#pragma unroll
            for (int j = 0; j < 4; ++j)
                sm[(mt * 16 + g * 4 + j) * 264 + h * 32 + nt * 16 + r16] =
                    f2bf(o[mt][nt][j]);
    __syncthreads();

    // ---- Phase 3: proj GEMM, wave w owns output cols [32w, 32w+32) ----
    f32x4 c3[4][2];
#pragma unroll
    for (int mt = 0; mt < 4; ++mt)
#pragma unroll
        for (int nt = 0; nt < 2; ++nt) c3[mt][nt] = zero4;
#pragma unroll
    for (int ks = 0; ks < 8; ++ks) {
        bf16x8 a3[4];
#pragma unroll
        for (int mt = 0; mt < 4; ++mt)
            a3[mt] = lds8(&sm[(mt * 16 + r16) * 264 + ks * 32 + g * 8]);
#pragma unroll
        for (int nt = 0; nt < 2; ++nt) {
            const unsigned short* wp =
                proj_wb + (wid * 32 + nt * 16 + r16) * 256 + ks * 32 + g * 8;
            bf16x8 b3 = *reinterpret_cast<const bf16x8*>(wp);
#pragma unroll
            for (int mt = 0; mt < 4; ++mt)
                c3[mt][nt] = mfma16(a3[mt], b3, c3[mt][nt]);
        }
    }
    float* og = out + (size_t)win * 16384;
#pragma unroll
    for (int nt = 0; nt < 2; ++nt) {
        int n = wid * 32 + nt * 16 + r16;
        float pb = proj_b[n];
#pragma unroll
        for (int mt = 0; mt < 4; ++mt)
#pragma unroll
            for (int j = 0; j < 4; ++j)
                og[(size_t)(mt * 16 + g * 4 + j) * 256 + n] = c3[mt][nt][j] + pb;
    }
}

extern "C" void kernel_launch(void* const* d_in, const int* in_sizes, int n_in,
                              void* d_out, int out_size, void* d_ws, size_t ws_size,
                              hipStream_t stream) {
    const float* x          = (const float*)d_in[0];
    const float* qkv_w      = (const float*)d_in[1];
    const float* qkv_b      = (const float*)d_in[2];
    const float* proj_w     = (const float*)d_in[3];
    const float* proj_b     = (const float*)d_in[4];
    const float* bias_table = (const float*)d_in[5];
    const int*   rel_index  = (const int*)d_in[6];

    // ws layout: qkv_wb bf16 (393216 B) | proj_wb bf16 (131072 B) | biasF f32 (131072 B)
    unsigned short* qkv_wb = (unsigned short*)d_ws;
    unsigned short* proj_wb = (unsigned short*)((char*)d_ws + 393216);
    float* biasF = (float*)((char*)d_ws + 524288);

    prep_kernel<<<256, 256, 0, stream>>>(qkv_w, proj_w, bias_table, rel_index,
                                         qkv_wb, proj_wb, biasF);
    win_attn_kernel<<<4096, 512, 0, stream>>>(x, qkv_b, proj_b, qkv_wb, proj_wb,
                                              biasF, (float*)d_out);
}